// Round 1
// baseline (9867.675 us; speedup 1.0000x reference)
//
#include <hip/hip_runtime.h>
#include <hip/hip_bf16.h>

// Problem constants
#define HH     1024
#define BB     64
#define DIN    768
#define TAUD   500
#define LSTEPS 127      // 1 audio step + 126 one-hot steps
#define G4     4096
#define NBLK   256

typedef __attribute__((ext_vector_type(8))) short bf16x8;
typedef __attribute__((ext_vector_type(4))) float f32x4;
typedef unsigned short u16;

__device__ __forceinline__ u16 f2b(float x){
  __hip_bfloat16 h = __float2bfloat16(x);
  return __builtin_bit_cast(u16, h);
}
__device__ __forceinline__ float b2f(u16 u){
  unsigned int x = ((unsigned int)u) << 16;
  return __builtin_bit_cast(float, x);
}
__device__ __forceinline__ float sig_(float x){ return 1.0f/(1.0f+__expf(-x)); }
__device__ __forceinline__ float tanh_(float x){
  float ax = fabsf(x);
  float e  = __expf(-2.0f*ax);
  float t  = (1.0f-e)/(1.0f+e);
  return x < 0.0f ? -t : t;
}

// ---------------- workspace layout (bytes). Total ~61.3 MB ----------------
constexpr size_t SZ_W    = (size_t)G4*HH;                  // elems of 4Hx H weights
constexpr size_t O_WIH0  = 0;                              // bf16 [4096,1024]
constexpr size_t O_WHH0  = O_WIH0  + SZ_W*2;
constexpr size_t O_WIH1  = O_WHH0  + SZ_W*2;
constexpr size_t O_WHH1  = O_WIH1  + SZ_W*2;
constexpr size_t O_WOHI  = O_WHH1  + SZ_W*2;               // bf16 [1024,1024]
constexpr size_t O_WOLO  = O_WOHI  + (size_t)HH*HH*2;
constexpr size_t O_WIH0T = O_WOLO  + (size_t)HH*HH*2;      // bf16 [1024,4096] (W_ih0^T)
constexpr size_t O_B0    = O_WIH0T + SZ_W*2;               // f32 [4096]
constexpr size_t O_B1    = O_B0    + G4*4;
constexpr size_t O_MEAN  = O_B1    + G4*4;                 // f32 [64,768]
constexpr size_t O_X0    = O_MEAN  + (size_t)BB*DIN*4;     // bf16 [64,1024]
constexpr size_t O_H0    = O_X0    + (size_t)BB*HH*2;      // bf16 [2][64][1024]
constexpr size_t O_H1    = O_H0    + (size_t)2*BB*HH*2;
constexpr size_t O_C0    = O_H1    + (size_t)2*BB*HH*2;    // f32 [64][1024]
constexpr size_t O_C1    = O_C0    + (size_t)BB*HH*4;
constexpr size_t O_HS    = O_C1    + (size_t)BB*HH*4;      // bf16 [127][64][1024]
constexpr size_t O_BAR   = O_HS    + (size_t)LSTEPS*BB*HH*2; // barrier ints

// ---------------- init: zero states + barrier (ws is poisoned 0xAA) -------
__global__ void init_kernel(u16* h0, u16* h1, float* c0, float* c1, int* bar){
  int i = blockIdx.x*256 + threadIdx.x;
  int st = gridDim.x*256;
  for (int k=i;k<2*BB*HH;k+=st){ h0[k]=0; h1[k]=0; }
  for (int k=i;k<BB*HH;k+=st){ c0[k]=0.0f; c1[k]=0.0f; }
  if (i < 64) bar[i] = 0;
}

// ---------------- audio mean-pool (mean is linear: pool before project) ---
__global__ void pool_kernel(const float* __restrict__ audio, float* __restrict__ mean){
  int b = blockIdx.x/3, dc = blockIdx.x%3;
  int d = dc*256 + threadIdx.x;
  const float* p = audio + (size_t)b*TAUD*DIN + d;
  float s = 0.f;
  #pragma unroll 5
  for (int t=0;t<TAUD;++t) s += p[(size_t)t*DIN];
  mean[b*DIN + d] = s*(1.0f/TAUD);
}

// ---------------- project pooled audio: x0[b,h] (fp32 math, bf16 out) -----
__global__ void project_kernel(const float* __restrict__ mean, const float* __restrict__ Wp,
                               const float* __restrict__ bp, u16* __restrict__ x0){
  __shared__ float wrow[DIN];
  __shared__ float part[256];
  int h = blockIdx.x;
  for (int i=threadIdx.x;i<DIN;i+=256) wrow[i] = Wp[(size_t)h*DIN + i];
  __syncthreads();
  int b = threadIdx.x>>2, q = threadIdx.x&3;
  const float* mr = mean + b*DIN + q*192;
  const float* wr = wrow + q*192;
  float s = 0.f;
  #pragma unroll 8
  for (int i=0;i<192;++i) s += mr[i]*wr[i];
  part[threadIdx.x] = s;
  __syncthreads();
  if (q==0){
    float v = part[threadIdx.x]+part[threadIdx.x+1]+part[threadIdx.x+2]+part[threadIdx.x+3] + bp[h];
    x0[b*HH + h] = f2b(v);
  }
}

// ---------------- weight converts ----------------------------------------
__global__ void cvt_kernel(const float* __restrict__ src, u16* __restrict__ dst, int n){
  int i = blockIdx.x*256+threadIdx.x, st = gridDim.x*256;
  for (;i<n;i+=st) dst[i] = f2b(src[i]);
}
// W_out split into bf16 hi + lo for extra precision on final GEMM
__global__ void wout_kernel(const float* __restrict__ src, u16* __restrict__ hi,
                            u16* __restrict__ lo, int n){
  int i = blockIdx.x*256+threadIdx.x, st = gridDim.x*256;
  for (;i<n;i+=st){
    float v = src[i];
    u16 h = f2b(v);
    hi[i] = h;
    lo[i] = f2b(v - b2f(h));
  }
}
__global__ void bias_kernel(const float* a0, const float* b0, const float* a1, const float* b1,
                            float* o0, float* o1){
  int i = blockIdx.x*256+threadIdx.x;
  if (i < G4){ o0[i]=a0[i]+b0[i]; o1[i]=a1[i]+b1[i]; }
}
// W_ih0 [4096,1024] f32 -> W_ih0^T [1024,4096] bf16 (for one-hot row gather)
__global__ void transpose_kernel(const float* __restrict__ in, u16* __restrict__ out){
  __shared__ float tile[32][33];
  int cb = blockIdx.x*32;   // K dim (1024)
  int rb = blockIdx.y*32;   // N dim (4096)
  int c = cb + threadIdx.x;
  for (int i=threadIdx.y;i<32;i+=8) tile[i][threadIdx.x] = in[(size_t)(rb+i)*HH + c];
  __syncthreads();
  int oc = rb + threadIdx.x;
  for (int i=threadIdx.y;i<32;i+=8) out[(size_t)(cb+i)*G4 + oc] = f2b(tile[threadIdx.x][i]);
}

// ---------------- device-scope grid barrier -------------------------------
__device__ __forceinline__ void gridbar(int* cnt, int* gen){
  __syncthreads();
  if (threadIdx.x==0){
    __threadfence();
    int g = __hip_atomic_load(gen, __ATOMIC_RELAXED, __HIP_MEMORY_SCOPE_AGENT);
    int a = __hip_atomic_fetch_add(cnt, 1, __ATOMIC_ACQ_REL, __HIP_MEMORY_SCOPE_AGENT);
    if (a == (int)gridDim.x-1){
      __hip_atomic_store(cnt, 0,   __ATOMIC_RELAXED, __HIP_MEMORY_SCOPE_AGENT);
      __hip_atomic_store(gen, g+1, __ATOMIC_RELEASE, __HIP_MEMORY_SCOPE_AGENT);
    } else {
      int gg;
      do {
        __builtin_amdgcn_s_sleep(8);
        gg = __hip_atomic_load(gen, __ATOMIC_ACQUIRE, __HIP_MEMORY_SCOPE_AGENT);
      } while (gg == g);
    }
    __threadfence();
  }
  __syncthreads();
}

// K=1024 MFMA dot: gates[m,n] += sum_k A[m,k]*W[n,k]
// A fragment: A[m=lane&15][k=quad*8+j]; B fragment: W[n=lane&15][k=quad*8+j]
__device__ __forceinline__ f32x4 gemm_k1024(const u16* __restrict__ A, const u16* __restrict__ Bm,
                                            int arow, int nglob, int quad, f32x4 acc){
  const u16* ap = A  + (size_t)arow*HH  + quad*8;
  const u16* bp = Bm + (size_t)nglob*HH + quad*8;
  #pragma unroll 8
  for (int kt=0;kt<32;++kt){
    bf16x8 a = *(const bf16x8*)(ap + kt*32);
    bf16x8 b = *(const bf16x8*)(bp + kt*32);
    acc = __builtin_amdgcn_mfma_f32_16x16x32_bf16(a, b, acc, 0, 0, 0);
  }
  return acc;
}

// ---------------- persistent 2-layer LSTM over 127 steps ------------------
// Block bid owns j-columns [bid*4, bid*4+4) of the hidden state, for both
// layers: MFMA C-tile columns map to n = j0+(col&3) + (col>>2)*1024 so that
// the block holds all 4 gates (i,f,g,o) of its j-columns -> cell math is
// block-local. One grid barrier per step (between layer0-cell and layer1):
// h0/h1 are double-buffered, c0/c1 are block-private columns.
__global__ void __launch_bounds__(256) lstm_kernel(
    const u16* __restrict__ Wih0, const u16* __restrict__ Whh0,
    const u16* __restrict__ Wih1, const u16* __restrict__ Whh1,
    const u16* __restrict__ Wih0T, const float* __restrict__ bias0,
    const float* __restrict__ bias1, const u16* __restrict__ x0bf,
    const int* __restrict__ tix,
    u16* __restrict__ h0bf, u16* __restrict__ h1bf,
    float* __restrict__ c0, float* __restrict__ c1,
    u16* __restrict__ hs, int* __restrict__ bar)
{
  const int tid  = threadIdx.x;
  const int w    = tid>>6, lane = tid&63, quad = lane>>4, col = lane&15;
  const int j0   = blockIdx.x*4;
  const int nglob = j0 + (col&3) + (col>>2)*HH;
  const int cb = tid>>2, cjj = tid&3, cj = j0+cjj;
  __shared__ float ldsg[BB*16];
  int* cnt = bar; int* gen = bar + 16;

  #pragma unroll 1
  for (int t=0;t<LSTEPS;++t){
    const int cur = t&1, nxt = cur^1;
    // -------- Phase A: layer0 gates + cell --------
    {
      const u16* A  = (t==0)? x0bf : (h0bf + (size_t)cur*BB*HH);
      const u16* Bm = (t==0)? Wih0 : Whh0;   // t=0: dense audio input GEMM
      f32x4 acc = {0.f,0.f,0.f,0.f};
      acc = gemm_k1024(A, Bm, w*16+col, nglob, quad, acc);
      float bge = bias0[nglob];
      #pragma unroll
      for (int r=0;r<4;++r){
        int b_ = w*16 + quad*4 + r;
        float v = acc[r] + bge;
        if (t>0) v += b2f(Wih0T[(size_t)tix[b_*128 + t]*G4 + nglob]); // one-hot gather
        ldsg[b_*16 + col] = v;
      }
      __syncthreads();
      float gi = ldsg[cb*16+cjj],   gf = ldsg[cb*16+4+cjj],
            gg = ldsg[cb*16+8+cjj], go = ldsg[cb*16+12+cjj];
      float cold = c0[cb*HH+cj];
      float cn = sig_(gf)*cold + sig_(gi)*tanh_(gg);
      float hn = sig_(go)*tanh_(cn);
      c0[cb*HH+cj] = cn;
      h0bf[(size_t)nxt*BB*HH + cb*HH + cj] = f2b(hn);
    }
    gridbar(cnt, gen);   // h0_t visible to all blocks before layer1
    // -------- Phase B: layer1 gates + cell --------
    {
      f32x4 acc = {0.f,0.f,0.f,0.f};
      acc = gemm_k1024(h0bf + (size_t)nxt*BB*HH, Wih1, w*16+col, nglob, quad, acc);
      acc = gemm_k1024(h1bf + (size_t)cur*BB*HH, Whh1, w*16+col, nglob, quad, acc);
      float bge = bias1[nglob];
      #pragma unroll
      for (int r=0;r<4;++r)
        ldsg[(w*16+quad*4+r)*16 + col] = acc[r] + bge;
      __syncthreads();
      float gi = ldsg[cb*16+cjj],   gf = ldsg[cb*16+4+cjj],
            gg = ldsg[cb*16+8+cjj], go = ldsg[cb*16+12+cjj];
      float cold = c1[cb*HH+cj];
      float cn = sig_(gf)*cold + sig_(gi)*tanh_(gg);
      float hn = sig_(go)*tanh_(cn);
      c1[cb*HH+cj] = cn;
      u16 hb = f2b(hn);
      h1bf[(size_t)nxt*BB*HH + cb*HH + cj] = hb;
      hs[((size_t)t*BB + cb)*HH + cj] = hb;
      __syncthreads();  // ldsg reuse guard before next iteration
    }
  }
}

// ---------------- logits: [8128,1024] @ W_out^T (bf16 hi+lo), +b_out ------
// 64 blocks x 8 waves; wave = one m-tile (16 rows of hs), A-frags in regs,
// W_out tiles staged in LDS (padded stride 1032 u16 -> 2-way bank alias only)
__global__ void __launch_bounds__(512) logits_kernel(
    const u16* __restrict__ hs, const u16* __restrict__ Whi, const u16* __restrict__ Wlo,
    const float* __restrict__ bout, float* __restrict__ out)
{
  extern __shared__ u16 bsh[];   // 2 * 16 * 1032 u16 = 66048 B
  const int tid = threadIdx.x;
  const int w = tid>>6, lane = tid&63, quad = lane>>4, col = lane&15;
  const int mt = blockIdx.x*8 + w;
  const bool active = (mt < (LSTEPS*BB)/16);   // 508 m-tiles
  bf16x8 afr[32];
  if (active){
    const u16* ap = hs + (size_t)(mt*16+col)*HH + quad*8;
    #pragma unroll
    for (int kt=0;kt<32;++kt) afr[kt] = *(const bf16x8*)(ap + kt*32);
  }
  for (int nt=0; nt<64; ++nt){
    __syncthreads();
    #pragma unroll
    for (int i=0;i<8;++i){
      int cid = i*512 + tid;          // 4096 chunks of 16B (hi then lo)
      int mat = cid>>11;
      int r = (cid>>7)&15, ck = cid&127;
      const u16* src = (mat? Wlo : Whi) + (size_t)(nt*16+r)*HH + ck*8;
      *(bf16x8*)(bsh + mat*16512 + r*1032 + ck*8) = *(const bf16x8*)src;
    }
    __syncthreads();
    if (active){
      f32x4 acc = {0.f,0.f,0.f,0.f};
      const u16* bh = bsh + col*1032 + quad*8;
      const u16* bl = bsh + 16512 + col*1032 + quad*8;
      #pragma unroll 8
      for (int kt=0;kt<32;++kt){
        bf16x8 b1 = *(const bf16x8*)(bh + kt*32);
        acc = __builtin_amdgcn_mfma_f32_16x16x32_bf16(afr[kt], b1, acc, 0,0,0);
        bf16x8 b2 = *(const bf16x8*)(bl + kt*32);
        acc = __builtin_amdgcn_mfma_f32_16x16x32_bf16(afr[kt], b2, acc, 0,0,0);
      }
      float bb = bout[nt*16 + col];
      #pragma unroll
      for (int r=0;r<4;++r){
        int m = mt*16 + quad*4 + r;
        int tt = m>>6, b_ = m&63;
        out[((size_t)b_*LSTEPS + tt)*HH + nt*16 + col] = acc[r] + bb;
      }
    }
  }
}

extern "C" void kernel_launch(void* const* d_in, const int* in_sizes, int n_in,
                              void* d_out, int out_size, void* d_ws, size_t ws_size,
                              hipStream_t stream) {
  const float* audio = (const float*)d_in[0];
  const int*   tix   = (const int*)  d_in[1];
  const float* Wproj = (const float*)d_in[2];
  const float* bproj = (const float*)d_in[3];
  const float* Wih0  = (const float*)d_in[4];
  const float* Whh0  = (const float*)d_in[5];
  const float* bih0  = (const float*)d_in[6];
  const float* bhh0  = (const float*)d_in[7];
  const float* Wih1  = (const float*)d_in[8];
  const float* Whh1  = (const float*)d_in[9];
  const float* bih1  = (const float*)d_in[10];
  const float* bhh1  = (const float*)d_in[11];
  const float* Wout  = (const float*)d_in[12];
  const float* bout  = (const float*)d_in[13];
  float* out = (float*)d_out;

  char* ws = (char*)d_ws;
  u16*   wWih0  = (u16*)  (ws + O_WIH0);
  u16*   wWhh0  = (u16*)  (ws + O_WHH0);
  u16*   wWih1  = (u16*)  (ws + O_WIH1);
  u16*   wWhh1  = (u16*)  (ws + O_WHH1);
  u16*   wWoHi  = (u16*)  (ws + O_WOHI);
  u16*   wWoLo  = (u16*)  (ws + O_WOLO);
  u16*   wWih0T = (u16*)  (ws + O_WIH0T);
  float* wB0    = (float*)(ws + O_B0);
  float* wB1    = (float*)(ws + O_B1);
  float* wMean  = (float*)(ws + O_MEAN);
  u16*   wX0    = (u16*)  (ws + O_X0);
  u16*   wH0    = (u16*)  (ws + O_H0);
  u16*   wH1    = (u16*)  (ws + O_H1);
  float* wC0    = (float*)(ws + O_C0);
  float* wC1    = (float*)(ws + O_C1);
  u16*   wHS    = (u16*)  (ws + O_HS);
  int*   wBar   = (int*)  (ws + O_BAR);

  init_kernel<<<64, 256, 0, stream>>>(wH0, wH1, wC0, wC1, wBar);
  pool_kernel<<<BB*3, 256, 0, stream>>>(audio, wMean);
  project_kernel<<<HH, 256, 0, stream>>>(wMean, Wproj, bproj, wX0);
  cvt_kernel<<<1024, 256, 0, stream>>>(Wih0, wWih0, (int)SZ_W);
  cvt_kernel<<<1024, 256, 0, stream>>>(Whh0, wWhh0, (int)SZ_W);
  cvt_kernel<<<1024, 256, 0, stream>>>(Wih1, wWih1, (int)SZ_W);
  cvt_kernel<<<1024, 256, 0, stream>>>(Whh1, wWhh1, (int)SZ_W);
  wout_kernel<<<512, 256, 0, stream>>>(Wout, wWoHi, wWoLo, HH*HH);
  bias_kernel<<<16, 256, 0, stream>>>(bih0, bhh0, bih1, bhh1, wB0, wB1);
  transpose_kernel<<<dim3(32,128), dim3(32,8), 0, stream>>>(Wih0, wWih0T);
  lstm_kernel<<<NBLK, 256, 0, stream>>>(wWih0, wWhh0, wWih1, wWhh1, wWih0T,
                                        wB0, wB1, wX0, tix, wH0, wH1, wC0, wC1,
                                        wHS, wBar);
  logits_kernel<<<64, 512, 66048, stream>>>(wHS, wWoHi, wWoLo, bout, out);
}

// Round 2
// 6149.022 us; speedup vs baseline: 1.6048x; 1.6048x over previous
//
#include <hip/hip_runtime.h>
#include <hip/hip_bf16.h>

// Problem constants
#define HH     1024
#define BB     64
#define DIN    768
#define TAUD   500
#define LSTEPS 127      // 1 audio step + 126 one-hot steps
#define G4     4096

typedef __attribute__((ext_vector_type(8))) short bf16x8;
typedef __attribute__((ext_vector_type(4))) float f32x4;
typedef unsigned short u16;

__device__ __forceinline__ u16 f2b(float x){
  __hip_bfloat16 h = __float2bfloat16(x);
  return __builtin_bit_cast(u16, h);
}
__device__ __forceinline__ float b2f(u16 u){
  unsigned int x = ((unsigned int)u) << 16;
  return __builtin_bit_cast(float, x);
}
__device__ __forceinline__ float sig_(float x){ return 1.0f/(1.0f+__expf(-x)); }
__device__ __forceinline__ float tanh_(float x){
  float ax = fabsf(x);
  float e  = __expf(-2.0f*ax);
  float t  = (1.0f-e)/(1.0f+e);
  return x < 0.0f ? -t : t;
}

// ---------------- workspace layout (bytes). Total ~55.3 MB ----------------
// R1 post-mortem: weight rows at power-of-2 strides (2MB gate stride, 2MB-aligned
// matrices) caused L2 set-aliasing -> 13.8MB/step HBM re-fetch -> latency-bound
// (0.9% MFMA, 200GB/s). Fix: per-block contiguous packed blobs in wave access order.
constexpr size_t O_PACK  = 0;                               // bf16 [256][3][16384]
constexpr size_t O_WG    = O_PACK + (size_t)256*3*16384*2;  // bf16 [256][1024][16]
constexpr size_t O_WOHI  = O_WG   + (size_t)256*1024*16*2;  // bf16 [1024,1024]
constexpr size_t O_WOLO  = O_WOHI + (size_t)HH*HH*2;
constexpr size_t O_B0P   = O_WOLO + (size_t)HH*HH*2;        // f32 [256][16] packed bias l0
constexpr size_t O_B1P   = O_B0P  + G4*4;
constexpr size_t O_MEAN  = O_B1P  + G4*4;                   // f32 [64,768]
constexpr size_t O_X0    = O_MEAN + (size_t)BB*DIN*4;       // bf16 [64,1024]
constexpr size_t O_H0    = O_X0   + (size_t)BB*HH*2;        // bf16 [2][64][1024]
constexpr size_t O_H1    = O_H0   + (size_t)2*BB*HH*2;
constexpr size_t O_HS    = O_H1   + (size_t)2*BB*HH*2;      // bf16 [127][64][1024]
constexpr size_t O_BAR   = O_HS   + (size_t)LSTEPS*BB*HH*2; // barrier ints (512)

// ---------------- init: zero h states + barrier ---------------------------
__global__ void init_kernel(u16* h0, u16* h1, int* bar){
  int i = blockIdx.x*256 + threadIdx.x;
  int st = gridDim.x*256;
  for (int k=i;k<2*BB*HH;k+=st){ h0[k]=0; h1[k]=0; }
  if (i < 512) bar[i] = 0;
}

// ---------------- audio mean-pool (mean is linear: pool before project) ---
__global__ void pool_kernel(const float* __restrict__ audio, float* __restrict__ mean){
  int b = blockIdx.x/3, dc = blockIdx.x%3;
  int d = dc*256 + threadIdx.x;
  const float* p = audio + (size_t)b*TAUD*DIN + d;
  float s = 0.f;
  #pragma unroll 5
  for (int t=0;t<TAUD;++t) s += p[(size_t)t*DIN];
  mean[b*DIN + d] = s*(1.0f/TAUD);
}

// ---------------- project pooled audio: x0[b,h] (fp32 math, bf16 out) -----
__global__ void project_kernel(const float* __restrict__ mean, const float* __restrict__ Wp,
                               const float* __restrict__ bp, u16* __restrict__ x0){
  __shared__ float wrow[DIN];
  __shared__ float part[256];
  int h = blockIdx.x;
  for (int i=threadIdx.x;i<DIN;i+=256) wrow[i] = Wp[(size_t)h*DIN + i];
  __syncthreads();
  int b = threadIdx.x>>2, q = threadIdx.x&3;
  const float* mr = mean + b*DIN + q*192;
  const float* wr = wrow + q*192;
  float s = 0.f;
  #pragma unroll 8
  for (int i=0;i<192;++i) s += mr[i]*wr[i];
  part[threadIdx.x] = s;
  __syncthreads();
  if (q==0){
    float v = part[threadIdx.x]+part[threadIdx.x+1]+part[threadIdx.x+2]+part[threadIdx.x+3] + bp[h];
    x0[b*HH + h] = f2b(v);
  }
}

// ---------------- pack recurrent weights into per-block blobs -------------
// Blob element (bid, m, ktg, col, kk): value = Wm[n][ktg*32+kk],
// n = bid*4 + (col&3) + (col>>2)*1024.  Per (bid,m) = 32KB contiguous;
// per kt the wave's 64 lanes read one contiguous 1KB line.
__global__ void pack_w_kernel(const float* __restrict__ Whh0, const float* __restrict__ Wih1,
                              const float* __restrict__ Whh1, u16* __restrict__ P){
  int bid = blockIdx.x, m = blockIdx.y;
  const float* src = (m==0)? Whh0 : (m==1)? Wih1 : Whh1;
  u16* dst = P + ((size_t)bid*3 + m)*16384;
  for (int e = threadIdx.x; e < 16384; e += 256){
    int ktg = e>>9, col = (e>>5)&15, kk = e&31;
    int n = bid*4 + (col&3) + (col>>2)*HH;
    dst[e] = f2b(src[(size_t)n*HH + ktg*32 + kk]);
  }
}

// One-hot gather table: WG[bid][char][cjj*4+g] = W_ih0[bid*4+cjj+g*1024][char]
__global__ void pack_wg_kernel(const float* __restrict__ Wih0, u16* __restrict__ WG){
  int bid = blockIdx.x;
  for (int ch = threadIdx.x; ch < 1024; ch += 256){
    #pragma unroll
    for (int cjj=0;cjj<4;++cjj)
      #pragma unroll
      for (int g=0;g<4;++g)
        WG[((size_t)bid*1024 + ch)*16 + cjj*4 + g] =
          f2b(Wih0[(size_t)(bid*4 + cjj + g*HH)*HH + ch]);
  }
}

// Packed biases: Bp[bid*16 + cjj*4 + g] = b_ih[n]+b_hh[n], n = bid*4+cjj+g*1024
__global__ void pack_bias_kernel(const float* bih0, const float* bhh0,
                                 const float* bih1, const float* bhh1,
                                 float* B0p, float* B1p){
  int i = blockIdx.x*256 + threadIdx.x;
  if (i < G4){
    int bid = i>>4, r = i&15, cjj = r>>2, g = r&3;
    int n = bid*4 + cjj + g*HH;
    B0p[i] = bih0[n]+bhh0[n];
    B1p[i] = bih1[n]+bhh1[n];
  }
}

// W_out split into bf16 hi + lo for extra precision on final GEMM
__global__ void wout_kernel(const float* __restrict__ src, u16* __restrict__ hi,
                            u16* __restrict__ lo, int n){
  int i = blockIdx.x*256+threadIdx.x, st = gridDim.x*256;
  for (;i<n;i+=st){
    float v = src[i];
    u16 h = f2b(v);
    hi[i] = h;
    lo[i] = f2b(v - b2f(h));
  }
}

// ---------------- device-scope 2-level tree barrier (monotonic) -----------
// bar[leaf*16] for leaf 0..15 (64B apart), bar[256]=root, bar[272]=generation
__device__ __forceinline__ void gridbar_t(int* bar, int t){
  __syncthreads();
  if (threadIdx.x==0){
    __threadfence();
    int leaf = blockIdx.x>>4;
    int a = __hip_atomic_fetch_add(&bar[leaf*16], 1, __ATOMIC_ACQ_REL, __HIP_MEMORY_SCOPE_AGENT);
    if (a == t*16 + 15){
      int r = __hip_atomic_fetch_add(&bar[256], 1, __ATOMIC_ACQ_REL, __HIP_MEMORY_SCOPE_AGENT);
      if (r == t*16 + 15)
        __hip_atomic_store(&bar[272], t+1, __ATOMIC_RELEASE, __HIP_MEMORY_SCOPE_AGENT);
    }
    int g;
    do {
      __builtin_amdgcn_s_sleep(1);
      g = __hip_atomic_load(&bar[272], __ATOMIC_ACQUIRE, __HIP_MEMORY_SCOPE_AGENT);
    } while (g <= t);
    __threadfence();
  }
  __syncthreads();
}

// 8 MFMAs over a k-quarter (256 of 1024), packed-B layout
__device__ __forceinline__ f32x4 gemm8(const u16* __restrict__ ap, const u16* __restrict__ pp,
                                       f32x4 acc){
  #pragma unroll
  for (int kt=0;kt<8;++kt){
    bf16x8 a = *(const bf16x8*)(ap + kt*32);
    bf16x8 b = *(const bf16x8*)(pp + kt*512);
    acc = __builtin_amdgcn_mfma_f32_16x16x32_bf16(a, b, acc, 0, 0, 0);
  }
  return acc;
}
// t=0 only: B from original f32 W_ih0 (row-major), converted in-register
__device__ __forceinline__ f32x4 gemm8f(const u16* __restrict__ ap, const float* __restrict__ wp,
                                        f32x4 acc){
  #pragma unroll
  for (int kt=0;kt<8;++kt){
    bf16x8 a = *(const bf16x8*)(ap + kt*32);
    float4 f0 = *(const float4*)(wp + kt*32);
    float4 f1 = *(const float4*)(wp + kt*32 + 4);
    bf16x8 b;
    b[0]=(short)f2b(f0.x); b[1]=(short)f2b(f0.y); b[2]=(short)f2b(f0.z); b[3]=(short)f2b(f0.w);
    b[4]=(short)f2b(f1.x); b[5]=(short)f2b(f1.y); b[6]=(short)f2b(f1.z); b[7]=(short)f2b(f1.w);
    acc = __builtin_amdgcn_mfma_f32_16x16x32_bf16(a, b, acc, 0, 0, 0);
  }
  return acc;
}

// ---------------- persistent 2-layer LSTM over 127 steps ------------------
// 256 blocks x 1024 threads (16 waves = 4 m-groups x 4 k-quarters).
// Block bid owns j-columns [bid*4,bid*4+4) for both layers; MFMA n-cols map
// n = bid*4+(col&3)+(col>>2)*1024 (all 4 gates of its columns -> cell math
// block-local; c-state lives in cell-thread registers). One grid barrier/step.
__global__ void __launch_bounds__(1024) lstm_kernel(
    const float* __restrict__ Wih0f, const u16* __restrict__ P,
    const u16* __restrict__ WG, const float* __restrict__ B0p,
    const float* __restrict__ B1p, const u16* __restrict__ x0bf,
    const int* __restrict__ tix,
    u16* __restrict__ h0bf, u16* __restrict__ h1bf,
    u16* __restrict__ hs, int* __restrict__ bar)
{
  const int tid  = threadIdx.x;
  const int w    = tid>>6, lane = tid&63, quad = lane>>4, col = lane&15;
  const int mg   = w&3, kq = w>>2;
  const int bid  = blockIdx.x;
  const int nglob = bid*4 + (col&3) + (col>>2)*HH;
  const int arow  = mg*16 + col;
  const int aoff  = arow*HH + kq*256 + quad*8;   // A-fragment offset into h
  // cell threads: tid<256, (cb,cjj)
  const int cb = tid>>2, cjj = tid&3, cj = bid*4 + cjj;
  __shared__ float ldsg[4][64][20];              // stride 20 -> 2-way bank alias only

  const u16* Pblk = P + (size_t)bid*49152;
  const u16* P0 = Pblk + kq*4096 + col*32 + quad*8;          // Whh0
  const u16* P1 = P0 + 16384;                                 // Wih1
  const u16* P2 = P0 + 32768;                                 // Whh1

  float cc0 = 0.f, cc1 = 0.f;                    // block-private cell state
  float4 vb0 = {0,0,0,0}, vb1 = {0,0,0,0};
  if (tid < 256){
    vb0 = *(const float4*)(B0p + bid*16 + cjj*4);
    vb1 = *(const float4*)(B1p + bid*16 + cjj*4);
  }

  #pragma unroll 1
  for (int t=0;t<LSTEPS;++t){
    const int cur = t&1, nxt = cur^1;
    // -------- Phase A: layer0 gates + cell --------
    {
      f32x4 acc = {0.f,0.f,0.f,0.f};
      if (t==0){
        acc = gemm8f(x0bf + aoff, Wih0f + (size_t)nglob*HH + kq*256 + quad*8, acc);
      } else {
        acc = gemm8(h0bf + (size_t)cur*BB*HH + aoff, P0, acc);
      }
      #pragma unroll
      for (int r=0;r<4;++r) ldsg[kq][mg*16 + quad*4 + r][col] = acc[r];
      __syncthreads();
      if (tid < 256){
        float gi = ldsg[0][cb][cjj]    + ldsg[1][cb][cjj]    + ldsg[2][cb][cjj]    + ldsg[3][cb][cjj]    + vb0.x;
        float gf = ldsg[0][cb][4+cjj]  + ldsg[1][cb][4+cjj]  + ldsg[2][cb][4+cjj]  + ldsg[3][cb][4+cjj]  + vb0.y;
        float gg = ldsg[0][cb][8+cjj]  + ldsg[1][cb][8+cjj]  + ldsg[2][cb][8+cjj]  + ldsg[3][cb][8+cjj]  + vb0.z;
        float go = ldsg[0][cb][12+cjj] + ldsg[1][cb][12+cjj] + ldsg[2][cb][12+cjj] + ldsg[3][cb][12+cjj] + vb0.w;
        if (t>0){
          int ch = tix[cb*128 + t];    // one-hot input = gathered W_ih0 column
          ushort4 wv = *(const ushort4*)(WG + ((size_t)bid*1024 + ch)*16 + cjj*4);
          gi += b2f(wv.x); gf += b2f(wv.y); gg += b2f(wv.z); go += b2f(wv.w);
        }
        cc0 = sig_(gf)*cc0 + sig_(gi)*tanh_(gg);
        float hn = sig_(go)*tanh_(cc0);
        h0bf[(size_t)nxt*BB*HH + cb*HH + cj] = f2b(hn);
      }
    }
    gridbar_t(bar, t);   // h0_t visible to all blocks before layer1
    // -------- Phase B: layer1 gates + cell --------
    {
      f32x4 z = {0.f,0.f,0.f,0.f};
      f32x4 a1 = gemm8(h0bf + (size_t)nxt*BB*HH + aoff, P1, z);
      f32x4 a2 = gemm8(h1bf + (size_t)cur*BB*HH + aoff, P2, z);
      f32x4 acc = a1 + a2;
      #pragma unroll
      for (int r=0;r<4;++r) ldsg[kq][mg*16 + quad*4 + r][col] = acc[r];
      __syncthreads();
      if (tid < 256){
        float gi = ldsg[0][cb][cjj]    + ldsg[1][cb][cjj]    + ldsg[2][cb][cjj]    + ldsg[3][cb][cjj]    + vb1.x;
        float gf = ldsg[0][cb][4+cjj]  + ldsg[1][cb][4+cjj]  + ldsg[2][cb][4+cjj]  + ldsg[3][cb][4+cjj]  + vb1.y;
        float gg = ldsg[0][cb][8+cjj]  + ldsg[1][cb][8+cjj]  + ldsg[2][cb][8+cjj]  + ldsg[3][cb][8+cjj]  + vb1.z;
        float go = ldsg[0][cb][12+cjj] + ldsg[1][cb][12+cjj] + ldsg[2][cb][12+cjj] + ldsg[3][cb][12+cjj] + vb1.w;
        cc1 = sig_(gf)*cc1 + sig_(gi)*tanh_(gg);
        float hn = sig_(go)*tanh_(cc1);
        u16 hb = f2b(hn);
        h1bf[(size_t)nxt*BB*HH + cb*HH + cj] = hb;
        hs[((size_t)t*BB + cb)*HH + cj] = hb;
      }
      __syncthreads();  // ldsg reuse guard before next iteration
    }
  }
}

// ---------------- logits: [8128,1024] @ W_out^T (bf16 hi+lo), +b_out ------
__global__ void __launch_bounds__(512) logits_kernel(
    const u16* __restrict__ hs, const u16* __restrict__ Whi, const u16* __restrict__ Wlo,
    const float* __restrict__ bout, float* __restrict__ out)
{
  extern __shared__ u16 bsh[];   // 2 * 16 * 1032 u16 = 66048 B
  const int tid = threadIdx.x;
  const int w = tid>>6, lane = tid&63, quad = lane>>4, col = lane&15;
  const int mt = blockIdx.x*8 + w;
  const bool active = (mt < (LSTEPS*BB)/16);   // 508 m-tiles
  bf16x8 afr[32];
  if (active){
    const u16* ap = hs + (size_t)(mt*16+col)*HH + quad*8;
    #pragma unroll
    for (int kt=0;kt<32;++kt) afr[kt] = *(const bf16x8*)(ap + kt*32);
  }
  for (int nt=0; nt<64; ++nt){
    __syncthreads();
    #pragma unroll
    for (int i=0;i<8;++i){
      int cid = i*512 + tid;          // 4096 chunks of 16B (hi then lo)
      int mat = cid>>11;
      int r = (cid>>7)&15, ck = cid&127;
      const u16* src = (mat? Wlo : Whi) + (size_t)(nt*16+r)*HH + ck*8;
      *(bf16x8*)(bsh + mat*16512 + r*1032 + ck*8) = *(const bf16x8*)src;
    }
    __syncthreads();
    if (active){
      f32x4 acc = {0.f,0.f,0.f,0.f};
      const u16* bh = bsh + col*1032 + quad*8;
      const u16* bl = bsh + 16512 + col*1032 + quad*8;
      #pragma unroll 8
      for (int kt=0;kt<32;++kt){
        bf16x8 b1 = *(const bf16x8*)(bh + kt*32);
        acc = __builtin_amdgcn_mfma_f32_16x16x32_bf16(afr[kt], b1, acc, 0,0,0);
        bf16x8 b2 = *(const bf16x8*)(bl + kt*32);
        acc = __builtin_amdgcn_mfma_f32_16x16x32_bf16(afr[kt], b2, acc, 0,0,0);
      }
      float bb = bout[nt*16 + col];
      #pragma unroll
      for (int r=0;r<4;++r){
        int m = mt*16 + quad*4 + r;
        int tt = m>>6, b_ = m&63;
        out[((size_t)b_*LSTEPS + tt)*HH + nt*16 + col] = acc[r] + bb;
      }
    }
  }
}

extern "C" void kernel_launch(void* const* d_in, const int* in_sizes, int n_in,
                              void* d_out, int out_size, void* d_ws, size_t ws_size,
                              hipStream_t stream) {
  const float* audio = (const float*)d_in[0];
  const int*   tix   = (const int*)  d_in[1];
  const float* Wproj = (const float*)d_in[2];
  const float* bproj = (const float*)d_in[3];
  const float* Wih0  = (const float*)d_in[4];
  const float* Whh0  = (const float*)d_in[5];
  const float* bih0  = (const float*)d_in[6];
  const float* bhh0  = (const float*)d_in[7];
  const float* Wih1  = (const float*)d_in[8];
  const float* Whh1  = (const float*)d_in[9];
  const float* bih1  = (const float*)d_in[10];
  const float* bhh1  = (const float*)d_in[11];
  const float* Wout  = (const float*)d_in[12];
  const float* bout  = (const float*)d_in[13];
  float* out = (float*)d_out;

  char* ws = (char*)d_ws;
  u16*   wP    = (u16*)  (ws + O_PACK);
  u16*   wWG   = (u16*)  (ws + O_WG);
  u16*   wWoHi = (u16*)  (ws + O_WOHI);
  u16*   wWoLo = (u16*)  (ws + O_WOLO);
  float* wB0p  = (float*)(ws + O_B0P);
  float* wB1p  = (float*)(ws + O_B1P);
  float* wMean = (float*)(ws + O_MEAN);
  u16*   wX0   = (u16*)  (ws + O_X0);
  u16*   wH0   = (u16*)  (ws + O_H0);
  u16*   wH1   = (u16*)  (ws + O_H1);
  u16*   wHS   = (u16*)  (ws + O_HS);
  int*   wBar  = (int*)  (ws + O_BAR);

  init_kernel<<<64, 256, 0, stream>>>(wH0, wH1, wBar);
  pool_kernel<<<BB*3, 256, 0, stream>>>(audio, wMean);
  project_kernel<<<HH, 256, 0, stream>>>(wMean, Wproj, bproj, wX0);
  pack_w_kernel<<<dim3(256,3), 256, 0, stream>>>(Whh0, Wih1, Whh1, wP);
  pack_wg_kernel<<<256, 256, 0, stream>>>(Wih0, wWG);
  pack_bias_kernel<<<16, 256, 0, stream>>>(bih0, bhh0, bih1, bhh1, wB0p, wB1p);
  wout_kernel<<<512, 256, 0, stream>>>(Wout, wWoHi, wWoLo, HH*HH);
  lstm_kernel<<<256, 1024, 0, stream>>>(Wih0, wP, wWG, wB0p, wB1p, wX0, tix,
                                        wH0, wH1, wHS, wBar);
  logits_kernel<<<64, 512, 66048, stream>>>(wHS, wWoHi, wWoLo, bout, out);
}

// Round 3
// 4445.100 us; speedup vs baseline: 2.2199x; 1.3833x over previous
//
#include <hip/hip_runtime.h>
#include <hip/hip_bf16.h>

// Problem constants
#define HH     1024
#define BB     64
#define DIN    768
#define TAUD   500
#define LSTEPS 127      // 1 audio step + 126 one-hot steps
#define G4     4096
#define NB     128      // lstm blocks; each owns 8 j-columns (32 gate rows)
#define BHH    (BB*HH)

typedef __attribute__((ext_vector_type(8))) short bf16x8;
typedef __attribute__((ext_vector_type(4))) float f32x4;
typedef unsigned short u16;
typedef unsigned long long u64;

__device__ __forceinline__ u16 f2b(float x){
  __hip_bfloat16 h = __float2bfloat16(x);
  return __builtin_bit_cast(u16, h);
}
__device__ __forceinline__ float b2f(u16 u){
  unsigned int x = ((unsigned int)u) << 16;
  return __builtin_bit_cast(float, x);
}
__device__ __forceinline__ float sig_(float x){ return 1.0f/(1.0f+__expf(-x)); }
__device__ __forceinline__ float tanh_(float x){
  float ax = fabsf(x);
  float e  = __expf(-2.0f*ax);
  float t  = (1.0f-e)/(1.0f+e);
  return x < 0.0f ? -t : t;
}

// ---------------- workspace layout (bytes), ~53 MB ------------------------
// R2 post-mortem: device-scope acquire at the grid barrier invalidates the
// whole per-XCD L2 every step (L2s aren't cross-coherent; coherence point is
// memory-side) -> weights refetched from L3 at ~700cyc each step -> 42us/step
// with all pipes <2%. R3: h state uses SYSTEM-scope relaxed atomics (sc0 sc1,
// L1+L2 bypass, coherent at memory side) + relaxed barrier (no invalidates).
// Weights stay L2-resident permanently.
constexpr size_t O_PACK  = 0;                                 // u16 [128][3][2 nt][32 ktg][16 col][32]
constexpr size_t O_WG    = O_PACK + (size_t)NB*3*32768*2;     // u16 [128][1024 ch][8 jj][4 g]
constexpr size_t O_WOHI  = O_WG   + (size_t)NB*1024*32*2;     // bf16 [1024,1024]
constexpr size_t O_WOLO  = O_WOHI + (size_t)HH*HH*2;
constexpr size_t O_B0P   = O_WOLO + (size_t)HH*HH*2;          // f32 [128][8 jj][4 g]
constexpr size_t O_B1P   = O_B0P  + G4*4;
constexpr size_t O_MEAN  = O_B1P  + G4*4;                     // f32 [64,768]
constexpr size_t O_X0    = O_MEAN + (size_t)BB*DIN*4;         // bf16 [64,1024]
constexpr size_t O_H0    = O_X0   + (size_t)BHH*2;            // bf16 [2][64][1024]
constexpr size_t O_H1    = O_H0   + (size_t)2*BHH*2;
constexpr size_t O_HS    = O_H1   + (size_t)2*BHH*2;          // bf16 [127][64][1024]
constexpr size_t O_BAR   = O_HS   + (size_t)LSTEPS*BHH*2;     // 512 ints

// ---------------- init: zero h states + barrier ---------------------------
__global__ void init_kernel(u16* h0, u16* h1, int* bar){
  int i = blockIdx.x*256 + threadIdx.x;
  int st = gridDim.x*256;
  for (int k=i;k<2*BHH;k+=st){ h0[k]=0; h1[k]=0; }
  if (i < 512) bar[i] = 0;
}

// ---------------- audio mean-pool (mean is linear: pool before project) ---
__global__ void pool_kernel(const float* __restrict__ audio, float* __restrict__ mean){
  int b = blockIdx.x/3, dc = blockIdx.x%3;
  int d = dc*256 + threadIdx.x;
  const float* p = audio + (size_t)b*TAUD*DIN + d;
  float s = 0.f;
  #pragma unroll 5
  for (int t=0;t<TAUD;++t) s += p[(size_t)t*DIN];
  mean[b*DIN + d] = s*(1.0f/TAUD);
}

// ---------------- project pooled audio: x0[b,h] (fp32 math, bf16 out) -----
__global__ void project_kernel(const float* __restrict__ mean, const float* __restrict__ Wp,
                               const float* __restrict__ bp, u16* __restrict__ x0){
  __shared__ float wrow[DIN];
  __shared__ float part[256];
  int h = blockIdx.x;
  for (int i=threadIdx.x;i<DIN;i+=256) wrow[i] = Wp[(size_t)h*DIN + i];
  __syncthreads();
  int b = threadIdx.x>>2, q = threadIdx.x&3;
  const float* mr = mean + b*DIN + q*192;
  const float* wr = wrow + q*192;
  float s = 0.f;
  #pragma unroll 8
  for (int i=0;i<192;++i) s += mr[i]*wr[i];
  part[threadIdx.x] = s;
  __syncthreads();
  if (q==0){
    float v = part[threadIdx.x]+part[threadIdx.x+1]+part[threadIdx.x+2]+part[threadIdx.x+3] + bp[h];
    x0[b*HH + h] = f2b(v);
  }
}

// ---------------- pack recurrent weights into per-block blobs -------------
// n_local = nt*16 + col in [0,32); n_global = bid*8 + (n_local&7) + (n_local>>3)*1024.
// Element (bid,m,nt,ktg,col,r) = Wm[n_global][ktg*32+r]. Per (m,nt): 32KB
// contiguous; per MFMA k-step a wave reads one contiguous 1KB line.
__global__ void pack_w_kernel(const float* __restrict__ Whh0, const float* __restrict__ Wih1,
                              const float* __restrict__ Whh1, u16* __restrict__ P){
  int bid = blockIdx.x, m = blockIdx.y;
  const float* src = (m==0)? Whh0 : (m==1)? Wih1 : Whh1;
  u16* dst = P + ((size_t)bid*3 + m)*32768;
  for (int e = threadIdx.x; e < 32768; e += 256){
    int r = e&31, colc = (e>>5)&15, ktg = (e>>9)&31, nt = e>>14;
    int nl = nt*16 + colc;
    int ng = bid*8 + (nl&7) + (nl>>3)*HH;
    dst[e] = f2b(src[(size_t)ng*HH + ktg*32 + r]);
  }
}

// One-hot gather table: WG[bid][ch][jj][g] = W_ih0[bid*8+jj+g*1024][ch]
__global__ void pack_wg_kernel(const float* __restrict__ Wih0, u16* __restrict__ WG){
  int bid = blockIdx.x;
  for (int ch = threadIdx.x; ch < 1024; ch += 256){
    #pragma unroll
    for (int jj=0;jj<8;++jj)
      #pragma unroll
      for (int g=0;g<4;++g)
        WG[((size_t)bid*1024 + ch)*32 + jj*4 + g] =
          f2b(Wih0[(size_t)(bid*8 + jj + g*HH)*HH + ch]);
  }
}

// Packed biases: Bp[(bid*8+jj)*4+g] = b_ih[n]+b_hh[n], n = bid*8+jj+g*1024
__global__ void pack_bias_kernel(const float* bih0, const float* bhh0,
                                 const float* bih1, const float* bhh1,
                                 float* B0p, float* B1p){
  int i = blockIdx.x*256 + threadIdx.x;
  if (i < G4){
    int bid = i>>5, jj = (i>>2)&7, g = i&3;
    int n = bid*8 + jj + g*HH;
    B0p[i] = bih0[n]+bhh0[n];
    B1p[i] = bih1[n]+bhh1[n];
  }
}

// W_out split into bf16 hi + lo for extra precision on final GEMM
__global__ void wout_kernel(const float* __restrict__ src, u16* __restrict__ hi,
                            u16* __restrict__ lo, int n){
  int i = blockIdx.x*256+threadIdx.x, st = gridDim.x*256;
  for (;i<n;i+=st){
    float v = src[i];
    u16 h = f2b(v);
    hi[i] = h;
    lo[i] = f2b(v - b2f(h));
  }
}

// ---------------- system-scope (L2-bypass) helpers ------------------------
__device__ __forceinline__ u64 sysld64(const u64* p){
  return __hip_atomic_load((u64*)p, __ATOMIC_RELAXED, __HIP_MEMORY_SCOPE_SYSTEM);
}
__device__ __forceinline__ void sysst32(unsigned* p, unsigned v){
  __hip_atomic_store(p, v, __ATOMIC_RELAXED, __HIP_MEMORY_SCOPE_SYSTEM);
}

// relaxed 2-level tree barrier: no acquire/release -> no L2 invalidation.
// Visibility: __syncthreads drains vmcnt(0) (sc0sc1 stores are then at the
// memory-side coherence point); all h traffic bypasses L1/L2 so no stale reads.
__device__ __forceinline__ void gridbar(int* bar, int t){
  __syncthreads();
  if (threadIdx.x==0){
    int leaf = blockIdx.x>>4;                     // 8 leaves x 16 blocks
    int a = __hip_atomic_fetch_add(&bar[leaf*32], 1, __ATOMIC_RELAXED, __HIP_MEMORY_SCOPE_SYSTEM);
    if (a == t*16 + 15)
      __hip_atomic_fetch_add(&bar[256], 1, __ATOMIC_RELAXED, __HIP_MEMORY_SCOPE_SYSTEM);
    while (__hip_atomic_load(&bar[256], __ATOMIC_RELAXED, __HIP_MEMORY_SCOPE_SYSTEM) < (t+1)*8)
      __builtin_amdgcn_s_sleep(1);
    asm volatile("" ::: "memory");
  }
  __syncthreads();
}

// stage 128KB (64x1024 bf16) global -> LDS via system loads (L1/L2 bypass)
#define HBS 1032   // hbuf row stride in u16 (1024 + 8 pad; dword stride 516 -> conflict-free A-frags)
__device__ __forceinline__ void stage_h(const u16* __restrict__ src, u16* hb){
  const u64* s64 = (const u64*)src;
  int tid = threadIdx.x;
  u64 v[16];
  #pragma unroll
  for (int i=0;i<16;++i) v[i] = sysld64(s64 + i*1024 + tid);
  #pragma unroll
  for (int i=0;i<16;++i){
    int f = (i*1024 + tid)*4;          // u16 flat index in [0,65536)
    int row = f >> 10, colk = f & 1023;
    *(u64*)(hb + row*HBS + colk) = v[i];
  }
}

// 16-MFMA K-chunk (512 of 1024), packed bf16 B
__device__ __forceinline__ f32x4 gemm16(const u16* __restrict__ hrow, const u16* __restrict__ bp,
                                        f32x4 acc){
  #pragma unroll
  for (int kt=0;kt<16;++kt){
    bf16x8 a = *(const bf16x8*)(hrow + kt*32);
    bf16x8 b = *(const bf16x8*)(bp + kt*512);
    acc = __builtin_amdgcn_mfma_f32_16x16x32_bf16(a, b, acc, 0, 0, 0);
  }
  return acc;
}
// t=0 only: B from f32 W_ih0 rows, converted in-register
__device__ __forceinline__ f32x4 gemm16f(const u16* __restrict__ hrow, const float* __restrict__ wr,
                                         f32x4 acc){
  #pragma unroll
  for (int kt=0;kt<16;++kt){
    bf16x8 a = *(const bf16x8*)(hrow + kt*32);
    float4 f0 = *(const float4*)(wr + kt*32);
    float4 f1 = *(const float4*)(wr + kt*32 + 4);
    bf16x8 b;
    b[0]=(short)f2b(f0.x); b[1]=(short)f2b(f0.y); b[2]=(short)f2b(f0.z); b[3]=(short)f2b(f0.w);
    b[4]=(short)f2b(f1.x); b[5]=(short)f2b(f1.y); b[6]=(short)f2b(f1.z); b[7]=(short)f2b(f1.w);
    acc = __builtin_amdgcn_mfma_f32_16x16x32_bf16(a, b, acc, 0, 0, 0);
  }
  return acc;
}

#define GIDX(ksl,m,n) (((ksl)*64 + (m))*34 + (n))   // gates LDS index (pad 34)

// ---------------- persistent 2-layer LSTM over 127 steps ------------------
// 128 blocks x 1024 threads (16 waves = nt(2) x mg(4) x ksl(2)).
// Block owns 8 j-cols -> 32 gate rows; full-h staged to LDS per GEMM via
// system loads; weights stream from (now stable) L2; one relaxed grid
// barrier per step; c-state in cell-thread registers.
__global__ void __launch_bounds__(1024) lstm_kernel(
    const float* __restrict__ Wih0f, const u16* __restrict__ P,
    const u16* __restrict__ WG, const float* __restrict__ B0p,
    const float* __restrict__ B1p, const u16* __restrict__ x0bf,
    const int* __restrict__ tix,
    u16* __restrict__ h0bf, u16* __restrict__ h1bf,
    u16* __restrict__ hs, int* __restrict__ bar)
{
  extern __shared__ char smem[];
  u16*   hbuf  = (u16*)smem;                       // 64 x 1032 u16 = 132096 B
  float* gates = (float*)(smem + 64*HBS*2);        // [2][64][34] f32 = 17408 B

  const int tid  = threadIdx.x;
  const int w    = tid>>6, lane = tid&63, quad = lane>>4, colc = lane&15;
  const int nt   = w&1, mg = (w>>1)&3, ksl = w>>3;
  const int bid  = blockIdx.x;
  const int nl   = nt*16 + colc;
  const int ng   = bid*8 + (nl&7) + (nl>>3)*HH;    // global gate row (t=0 f32 path)
  const u16* hrow0 = hbuf + (mg*16 + colc)*HBS + ksl*512 + quad*8;
  // packed weight bases for this wave (per (m,nt) 16384-u16 blocks)
  const size_t pbase = ((size_t)bid*3*2 + nt)*16384 + ksl*8192 + colc*32 + quad*8;
  const u16* P0 = P + pbase;            // Whh0  (m=0)
  const u16* P1 = P0 + 2*16384;         // Wih1  (m=1)
  const u16* P2 = P0 + 4*16384;         // Whh1  (m=2)

  // cell threads: tid<512 -> (b, jj)
  const int cb = tid>>3, cjj = tid&7;
  float cc0 = 0.f, cc1 = 0.f;
  float4 vb0 = {0,0,0,0}, vb1 = {0,0,0,0};
  if (tid < 512){
    vb0 = *(const float4*)(B0p + (bid*8+cjj)*4);
    vb1 = *(const float4*)(B1p + (bid*8+cjj)*4);
  }

  #pragma unroll 1
  for (int t=0;t<LSTEPS;++t){
    const int cur = t&1, nxt = cur^1;
    // -------- Phase A: layer0 gates + cell --------
    stage_h((t==0)? x0bf : (h0bf + (size_t)cur*BHH), hbuf);
    __syncthreads();
    {
      f32x4 acc = {0.f,0.f,0.f,0.f};
      if (t==0) acc = gemm16f(hrow0, Wih0f + (size_t)ng*HH + ksl*512 + quad*8, acc);
      else      acc = gemm16(hrow0, P0, acc);
      #pragma unroll
      for (int r=0;r<4;++r) gates[GIDX(ksl, mg*16 + quad*4 + r, nl)] = acc[r];
    }
    __syncthreads();
    if (tid < 512){
      float gv[4];
      #pragma unroll
      for (int g=0;g<4;++g)
        gv[g] = gates[GIDX(0,cb,g*8+cjj)] + gates[GIDX(1,cb,g*8+cjj)];
      gv[0]+=vb0.x; gv[1]+=vb0.y; gv[2]+=vb0.z; gv[3]+=vb0.w;
      if (t>0){
        int ch = tix[cb*128 + t];       // one-hot input = gathered W_ih0 column
        ushort4 wv = *(const ushort4*)(WG + ((size_t)bid*1024 + ch)*32 + cjj*4);
        gv[0]+=b2f(wv.x); gv[1]+=b2f(wv.y); gv[2]+=b2f(wv.z); gv[3]+=b2f(wv.w);
      }
      cc0 = sig_(gv[1])*cc0 + sig_(gv[0])*tanh_(gv[2]);
      float hn = sig_(gv[3])*tanh_(cc0);
      unsigned hv = f2b(hn);
      unsigned ov = __shfl_xor(hv, 1);
      if ((cjj&1)==0)
        sysst32((unsigned*)(h0bf + (size_t)nxt*BHH) + (cb*HH + bid*8 + cjj)/2, hv | (ov<<16));
    }
    gridbar(bar, t);   // h0_t globally visible before layer1
    // -------- Phase B: layer1 gates + cell --------
    stage_h(h0bf + (size_t)nxt*BHH, hbuf);
    __syncthreads();
    f32x4 acc = {0.f,0.f,0.f,0.f};
    acc = gemm16(hrow0, P1, acc);
    __syncthreads();                 // all reads of hbuf done before overwrite
    stage_h(h1bf + (size_t)cur*BHH, hbuf);
    __syncthreads();
    acc = gemm16(hrow0, P2, acc);
    #pragma unroll
    for (int r=0;r<4;++r) gates[GIDX(ksl, mg*16 + quad*4 + r, nl)] = acc[r];
    __syncthreads();
    if (tid < 512){
      float gv[4];
      #pragma unroll
      for (int g=0;g<4;++g)
        gv[g] = gates[GIDX(0,cb,g*8+cjj)] + gates[GIDX(1,cb,g*8+cjj)];
      gv[0]+=vb1.x; gv[1]+=vb1.y; gv[2]+=vb1.z; gv[3]+=vb1.w;
      cc1 = sig_(gv[1])*cc1 + sig_(gv[0])*tanh_(gv[2]);
      float hn = sig_(gv[3])*tanh_(cc1);
      unsigned hv = f2b(hn);
      unsigned ov = __shfl_xor(hv, 1);
      if ((cjj&1)==0)
        sysst32((unsigned*)(h1bf + (size_t)nxt*BHH) + (cb*HH + bid*8 + cjj)/2, hv | (ov<<16));
      hs[((size_t)t*BB + cb)*HH + bid*8 + cjj] = (u16)hv;   // plain store, read by next kernel
    }
    // next loop's stage_h writes hbuf; gates readers are done at next sync.
  }
}

// ---------------- logits: [8128,1024] @ W_out^T (bf16 hi+lo), +b_out ------
__global__ void __launch_bounds__(512) logits_kernel(
    const u16* __restrict__ hs, const u16* __restrict__ Whi, const u16* __restrict__ Wlo,
    const float* __restrict__ bout, float* __restrict__ out)
{
  extern __shared__ u16 bsh[];   // 2 * 16 * 1032 u16 = 66048 B
  const int tid = threadIdx.x;
  const int w = tid>>6, lane = tid&63, quad = lane>>4, col = lane&15;
  const int mt = blockIdx.x*8 + w;
  const bool active = (mt < (LSTEPS*BB)/16);   // 508 m-tiles
  bf16x8 afr[32];
  if (active){
    const u16* ap = hs + (size_t)(mt*16+col)*HH + quad*8;
    #pragma unroll
    for (int kt=0;kt<32;++kt) afr[kt] = *(const bf16x8*)(ap + kt*32);
  }
  for (int nt=0; nt<64; ++nt){
    __syncthreads();
    #pragma unroll
    for (int i=0;i<8;++i){
      int cid = i*512 + tid;          // 4096 chunks of 16B (hi then lo)
      int mat = cid>>11;
      int r = (cid>>7)&15, ck = cid&127;
      const u16* src = (mat? Wlo : Whi) + (size_t)(nt*16+r)*HH + ck*8;
      *(bf16x8*)(bsh + mat*16512 + r*1032 + ck*8) = *(const bf16x8*)src;
    }
    __syncthreads();
    if (active){
      f32x4 acc = {0.f,0.f,0.f,0.f};
      const u16* bh = bsh + col*1032 + quad*8;
      const u16* bl = bsh + 16512 + col*1032 + quad*8;
      #pragma unroll 8
      for (int kt=0;kt<32;++kt){
        bf16x8 b1 = *(const bf16x8*)(bh + kt*32);
        acc = __builtin_amdgcn_mfma_f32_16x16x32_bf16(afr[kt], b1, acc, 0,0,0);
        bf16x8 b2 = *(const bf16x8*)(bl + kt*32);
        acc = __builtin_amdgcn_mfma_f32_16x16x32_bf16(afr[kt], b2, acc, 0,0,0);
      }
      float bb = bout[nt*16 + col];
      #pragma unroll
      for (int r=0;r<4;++r){
        int m = mt*16 + quad*4 + r;
        int tt = m>>6, b_ = m&63;
        out[((size_t)b_*LSTEPS + tt)*HH + nt*16 + col] = acc[r] + bb;
      }
    }
  }
}

extern "C" void kernel_launch(void* const* d_in, const int* in_sizes, int n_in,
                              void* d_out, int out_size, void* d_ws, size_t ws_size,
                              hipStream_t stream) {
  const float* audio = (const float*)d_in[0];
  const int*   tix   = (const int*)  d_in[1];
  const float* Wproj = (const float*)d_in[2];
  const float* bproj = (const float*)d_in[3];
  const float* Wih0  = (const float*)d_in[4];
  const float* Whh0  = (const float*)d_in[5];
  const float* bih0  = (const float*)d_in[6];
  const float* bhh0  = (const float*)d_in[7];
  const float* Wih1  = (const float*)d_in[8];
  const float* Whh1  = (const float*)d_in[9];
  const float* bih1  = (const float*)d_in[10];
  const float* bhh1  = (const float*)d_in[11];
  const float* Wout  = (const float*)d_in[12];
  const float* bout  = (const float*)d_in[13];
  float* out = (float*)d_out;

  char* ws = (char*)d_ws;
  u16*   wP    = (u16*)  (ws + O_PACK);
  u16*   wWG   = (u16*)  (ws + O_WG);
  u16*   wWoHi = (u16*)  (ws + O_WOHI);
  u16*   wWoLo = (u16*)  (ws + O_WOLO);
  float* wB0p  = (float*)(ws + O_B0P);
  float* wB1p  = (float*)(ws + O_B1P);
  float* wMean = (float*)(ws + O_MEAN);
  u16*   wX0   = (u16*)  (ws + O_X0);
  u16*   wH0   = (u16*)  (ws + O_H0);
  u16*   wH1   = (u16*)  (ws + O_H1);
  u16*   wHS   = (u16*)  (ws + O_HS);
  int*   wBar  = (int*)  (ws + O_BAR);

  init_kernel<<<64, 256, 0, stream>>>(wH0, wH1, wBar);
  pool_kernel<<<BB*3, 256, 0, stream>>>(audio, wMean);
  project_kernel<<<HH, 256, 0, stream>>>(wMean, Wproj, bproj, wX0);
  pack_w_kernel<<<dim3(NB,3), 256, 0, stream>>>(Whh0, Wih1, Whh1, wP);
  pack_wg_kernel<<<NB, 256, 0, stream>>>(Wih0, wWG);
  pack_bias_kernel<<<16, 256, 0, stream>>>(bih0, bhh0, bih1, bhh1, wB0p, wB1p);
  wout_kernel<<<512, 256, 0, stream>>>(Wout, wWoHi, wWoLo, HH*HH);
  lstm_kernel<<<NB, 1024, 64*HBS*2 + 2*64*34*4, stream>>>(
      Wih0, wP, wWG, wB0p, wB1p, wX0, tix, wH0, wH1, wHS, wBar);
  logits_kernel<<<64, 512, 66048, stream>>>(wHS, wWoHi, wWoLo, bout, out);
}